// Round 1
// baseline (422.782 us; speedup 1.0000x reference)
//
#include <hip/hip_runtime.h>
#include <hip/hip_bf16.h>
#include <cstdint>
#include <cstddef>

#define TQ 2048
#define CDIM 1024
#define NH 16
#define HD 64

typedef __attribute__((ext_vector_type(8))) short bf16x8;
typedef __attribute__((ext_vector_type(4))) float f32x4;

__device__ __forceinline__ unsigned short f2bf(float f) {
  union { float f; unsigned u; } x; x.f = f;
  unsigned r = x.u + 0x7fffu + ((x.u >> 16) & 1u);
  return (unsigned short)(r >> 16);
}

__device__ __forceinline__ void gload_lds16(const void* g, void* l) {
  typedef __attribute__((address_space(1))) const void gv;
  typedef __attribute__((address_space(3))) void lv;
  __builtin_amdgcn_global_load_lds((gv*)g, (lv*)l, 16, 0, 0);
}

// ---------------- fp32 -> bf16 convert ----------------
__global__ void cvt_bf16_kernel(const float* __restrict__ in,
                                unsigned short* __restrict__ out, int n) {
  int stride = gridDim.x * blockDim.x;
  for (int i = blockIdx.x * blockDim.x + threadIdx.x; i * 4 < n; i += stride) {
    float4 v = *(const float4*)(in + (size_t)i * 4);
    ushort4 o;
    o.x = f2bf(v.x); o.y = f2bf(v.y); o.z = f2bf(v.z); o.w = f2bf(v.w);
    *(ushort4*)(out + (size_t)i * 4) = o;
  }
}

// ---------------- GEMM: C[M,N] = A[M,K] * Bt[N,K]^T (+bias), bf16 in ----------------
// EPI 0: bf16 out -> [B,H,T,D]  (m=b*T+t, n=h*D+d), bias[n]
// EPI 1: bf16 out -> [B,H,D,T]  (m=h*D+d, n=b*T+t), bias[m]
// EPI 2: f32  out -> [M,N] row-major, bias[n]
template <int EPI>
__global__ __launch_bounds__(256) void gemm_bt_kernel(
    const unsigned short* __restrict__ A,
    const unsigned short* __restrict__ Bt,
    const float* __restrict__ bias,
    void* __restrict__ outp,
    int M, int N, int K) {
  __shared__ __align__(16) unsigned short As[128 * 64];
  __shared__ __align__(16) unsigned short Bs[128 * 64];

  const int nbm = M >> 7;
  const int nbn = N >> 7;
  const int nwg = nbm * nbn;
  int id = (int)blockIdx.x;
  // XCD-aware swizzle (all our grids have nwg % 8 == 0)
  const int cpx = nwg >> 3;
  id = (id & 7) * cpx + (id >> 3);
  const int tm = id % nbm;
  const int tn = id / nbm;

  const int tid = threadIdx.x;
  const int w = tid >> 6, lane = tid & 63;
  const int g = lane >> 4, c = lane & 15;
  const int wr = w >> 1, wc = w & 1;

  const unsigned short* Ab = A + (size_t)tm * 128 * K;
  const unsigned short* Bb = Bt + (size_t)tn * 128 * K;
  const int Kb = K * 2;  // row bytes

  f32x4 acc[4][4];
#pragma unroll
  for (int i = 0; i < 4; ++i)
#pragma unroll
    for (int j = 0; j < 4; ++j) acc[i][j] = (f32x4){0.f, 0.f, 0.f, 0.f};

  for (int kt = 0; kt < K; kt += 64) {
#pragma unroll
    for (int i = 0; i < 4; ++i) {
      const int seg = w * 4 + i;              // wave-uniform
      const int off = seg * 1024 + lane * 16; // byte offset in 16KB tile
      const int row = off >> 7;               // 128B per row (64 bf16)
      const int colB = off & 127;
      gload_lds16((const char*)Ab + (size_t)row * Kb + kt * 2 + colB,
                  (char*)As + seg * 1024);
      gload_lds16((const char*)Bb + (size_t)row * Kb + kt * 2 + colB,
                  (char*)Bs + seg * 1024);
    }
    __syncthreads();
#pragma unroll
    for (int ki = 0; ki < 2; ++ki) {
      bf16x8 af[4], bv[4];
#pragma unroll
      for (int mi = 0; mi < 4; ++mi)
        af[mi] = *(const bf16x8*)(As + (wr * 64 + mi * 16 + c) * 64 + ki * 32 + g * 8);
#pragma unroll
      for (int ni = 0; ni < 4; ++ni)
        bv[ni] = *(const bf16x8*)(Bs + (wc * 64 + ni * 16 + c) * 64 + ki * 32 + g * 8);
#pragma unroll
      for (int mi = 0; mi < 4; ++mi)
#pragma unroll
        for (int ni = 0; ni < 4; ++ni)
          acc[mi][ni] = __builtin_amdgcn_mfma_f32_16x16x32_bf16(
              af[mi], bv[ni], acc[mi][ni], 0, 0, 0);
    }
    __syncthreads();
  }

#pragma unroll
  for (int mi = 0; mi < 4; ++mi) {
#pragma unroll
    for (int ni = 0; ni < 4; ++ni) {
      const int n = tn * 128 + wc * 64 + ni * 16 + c;
#pragma unroll
      for (int e = 0; e < 4; ++e) {
        const int m = tm * 128 + wr * 64 + mi * 16 + g * 4 + e;
        float v = acc[mi][ni][e];
        if (EPI == 0) {
          v += bias[n];
          size_t idx = ((size_t)(m >> 11) * NH + (n >> 6)) * (TQ * HD) +
                       (size_t)(m & (TQ - 1)) * HD + (n & (HD - 1));
          ((unsigned short*)outp)[idx] = f2bf(v);
        } else if (EPI == 1) {
          v += bias[m];
          size_t idx = ((size_t)(n >> 11) * (NH * HD) + m) * TQ + (n & (TQ - 1));
          ((unsigned short*)outp)[idx] = f2bf(v);
        } else {
          v += bias[n];
          ((float*)outp)[(size_t)m * N + n] = v;
        }
      }
    }
  }
}

// ---------------- flash attention (causal) ----------------
// Q,K: [B,H,T,D] bf16 ; Vt: [B,H,D,T] bf16 ; Y: [B,T,C] bf16
__global__ __launch_bounds__(256) void attn_kernel(
    const unsigned short* __restrict__ Q,
    const unsigned short* __restrict__ K,
    const unsigned short* __restrict__ Vt,
    unsigned short* __restrict__ Y) {
  __shared__ __align__(16) unsigned short Plds[4][32][72];  // +8 pad: 2-way banks

  const int tid = threadIdx.x;
  const int w = tid >> 6, lane = tid & 63;
  const int g = lane >> 4, c = lane & 15;

  const int bh = blockIdx.y;
  const int b = bh >> 4, h = bh & 15;
  const int q0 = blockIdx.x * 128 + w * 32;  // this wave's 32 q-rows

  const unsigned short* Qb = Q + (size_t)bh * TQ * HD;
  const unsigned short* Kb = K + (size_t)bh * TQ * HD;
  const unsigned short* Vb = Vt + (size_t)bh * HD * TQ;

  // Q fragments: [rb][kd], row = q0+rb*16+c, k = kd*32+g*8
  bf16x8 qf[2][2];
#pragma unroll
  for (int rb = 0; rb < 2; ++rb)
#pragma unroll
    for (int kd = 0; kd < 2; ++kd)
      qf[rb][kd] = *(const bf16x8*)(Qb + (size_t)(q0 + rb * 16 + c) * HD + kd * 32 + g * 8);

  f32x4 acc[2][4];
#pragma unroll
  for (int i = 0; i < 2; ++i)
#pragma unroll
    for (int j = 0; j < 4; ++j) acc[i][j] = (f32x4){0.f, 0.f, 0.f, 0.f};
  float mr[2][4], lr[2][4];
#pragma unroll
  for (int i = 0; i < 2; ++i)
#pragma unroll
    for (int e = 0; e < 4; ++e) { mr[i][e] = -3.0e38f; lr[i][e] = 0.f; }

  const int nfull = q0 >> 6;
  for (int kt = 0; kt <= nfull; ++kt) {
    const int kvb = kt * 64;
    const bool maskT = (kt == nfull);

    // S = Q K^T : s[rb][cb], rows q0+rb*16+(g*4+e), cols kvb+cb*16+c
    f32x4 s[2][4];
#pragma unroll
    for (int i = 0; i < 2; ++i)
#pragma unroll
      for (int j = 0; j < 4; ++j) s[i][j] = (f32x4){0.f, 0.f, 0.f, 0.f};
#pragma unroll
    for (int cb = 0; cb < 4; ++cb) {
#pragma unroll
      for (int kd = 0; kd < 2; ++kd) {
        bf16x8 kf = *(const bf16x8*)(Kb + (size_t)(kvb + cb * 16 + c) * HD + kd * 32 + g * 8);
#pragma unroll
        for (int rb = 0; rb < 2; ++rb)
          s[rb][cb] = __builtin_amdgcn_mfma_f32_16x16x32_bf16(qf[rb][kd], kf, s[rb][cb], 0, 0, 0);
      }
    }

    // scale + causal mask
#pragma unroll
    for (int rb = 0; rb < 2; ++rb)
#pragma unroll
      for (int cb = 0; cb < 4; ++cb)
#pragma unroll
        for (int e = 0; e < 4; ++e) {
          float v = s[rb][cb][e] * 0.125f;
          if (maskT) {
            int kv = kvb + cb * 16 + c;
            int q = q0 + rb * 16 + g * 4 + e;
            if (kv > q) v = -3.0e38f;
          }
          s[rb][cb][e] = v;
        }

    // online softmax: rowmax (in-lane over cb, then 16-lane xor-reduce)
    float al[2][4];
#pragma unroll
    for (int rb = 0; rb < 2; ++rb)
#pragma unroll
      for (int e = 0; e < 4; ++e) {
        float v = fmaxf(fmaxf(s[rb][0][e], s[rb][1][e]), fmaxf(s[rb][2][e], s[rb][3][e]));
#pragma unroll
        for (int off = 1; off < 16; off <<= 1) v = fmaxf(v, __shfl_xor(v, off, 16));
        float mn = fmaxf(mr[rb][e], v);
        al[rb][e] = __expf(mr[rb][e] - mn);
        mr[rb][e] = mn;
      }

    // P = exp(S - m), row sums, l update
#pragma unroll
    for (int rb = 0; rb < 2; ++rb)
#pragma unroll
      for (int e = 0; e < 4; ++e) {
        float rs = 0.f;
#pragma unroll
        for (int cb = 0; cb < 4; ++cb) {
          float p = __expf(s[rb][cb][e] - mr[rb][e]);
          s[rb][cb][e] = p;
          rs += p;
        }
#pragma unroll
        for (int off = 1; off < 16; off <<= 1) rs += __shfl_xor(rs, off, 16);
        lr[rb][e] = lr[rb][e] * al[rb][e] + rs;
      }

    // rescale accumulator
#pragma unroll
    for (int rb = 0; rb < 2; ++rb)
#pragma unroll
      for (int db = 0; db < 4; ++db)
#pragma unroll
        for (int e = 0; e < 4; ++e) acc[rb][db][e] *= al[rb][e];

    // P -> LDS (bf16), then reload as A-fragments (same-wave DS ordering; no barrier)
#pragma unroll
    for (int rb = 0; rb < 2; ++rb)
#pragma unroll
      for (int cb = 0; cb < 4; ++cb)
#pragma unroll
        for (int e = 0; e < 4; ++e)
          Plds[w][rb * 16 + g * 4 + e][cb * 16 + c] = f2bf(s[rb][cb][e]);

    bf16x8 pa[2][2];
#pragma unroll
    for (int rb = 0; rb < 2; ++rb)
#pragma unroll
      for (int ks = 0; ks < 2; ++ks)
        pa[rb][ks] = *(const bf16x8*)(&Plds[w][rb * 16 + c][ks * 32 + g * 8]);

    // O += P V  (V consumed from transposed layout: 16B contiguous per lane)
#pragma unroll
    for (int db = 0; db < 4; ++db)
#pragma unroll
      for (int ks = 0; ks < 2; ++ks) {
        bf16x8 vf = *(const bf16x8*)(Vb + (size_t)(db * 16 + c) * TQ + kvb + ks * 32 + g * 8);
#pragma unroll
        for (int rb = 0; rb < 2; ++rb)
          acc[rb][db] = __builtin_amdgcn_mfma_f32_16x16x32_bf16(pa[rb][ks], vf, acc[rb][db], 0, 0, 0);
      }
  }

  // epilogue: Y[b][t][h*64+d] = acc / l
#pragma unroll
  for (int rb = 0; rb < 2; ++rb)
#pragma unroll
    for (int db = 0; db < 4; ++db)
#pragma unroll
      for (int e = 0; e < 4; ++e) {
        float o = acc[rb][db][e] / lr[rb][e];
        int t = q0 + rb * 16 + g * 4 + e;
        int col = h * 64 + db * 16 + c;
        Y[(size_t)(b * TQ + t) * CDIM + col] = f2bf(o);
      }
}

// ---------------- launcher ----------------
extern "C" void kernel_launch(void* const* d_in, const int* in_sizes, int n_in,
                              void* d_out, int out_size, void* d_ws, size_t ws_size,
                              hipStream_t stream) {
  (void)in_sizes; (void)n_in; (void)out_size; (void)ws_size;
  const float* x  = (const float*)d_in[0];
  const float* Wq = (const float*)d_in[1];
  const float* bq = (const float*)d_in[2];
  const float* Wk = (const float*)d_in[3];
  const float* bk = (const float*)d_in[4];
  const float* Wv = (const float*)d_in[5];
  const float* bv = (const float*)d_in[6];
  const float* Wp = (const float*)d_in[7];
  const float* bp = (const float*)d_in[8];
  float* out = (float*)d_out;

  char* ws = (char*)d_ws;
  unsigned short* xb  = (unsigned short*)(ws + 0);           // 16 MB
  unsigned short* wqb = (unsigned short*)(ws + 16777216);    // 2 MB
  unsigned short* wkb = (unsigned short*)(ws + 18874368);
  unsigned short* wvb = (unsigned short*)(ws + 20971520);
  unsigned short* wpb = (unsigned short*)(ws + 23068672);
  unsigned short* Qh  = (unsigned short*)(ws + 25165824);    // 16 MB [B,H,T,D]
  unsigned short* Kh  = (unsigned short*)(ws + 41943040);    // 16 MB
  unsigned short* Vt  = (unsigned short*)(ws + 58720256);    // 16 MB [B,H,D,T]
  unsigned short* y   = (unsigned short*)(ws + 75497472);    // 16 MB [B,T,C]

  const int nx = 4 * TQ * CDIM;     // 8388608
  const int nw = CDIM * CDIM;       // 1048576

  cvt_bf16_kernel<<<4096, 256, 0, stream>>>(x, xb, nx);
  cvt_bf16_kernel<<<1024, 256, 0, stream>>>(Wq, wqb, nw);
  cvt_bf16_kernel<<<1024, 256, 0, stream>>>(Wk, wkb, nw);
  cvt_bf16_kernel<<<1024, 256, 0, stream>>>(Wv, wvb, nw);
  cvt_bf16_kernel<<<1024, 256, 0, stream>>>(Wp, wpb, nw);

  // Q = x Wq^T -> [B,H,T,D] ; K likewise
  gemm_bt_kernel<0><<<512, 256, 0, stream>>>(xb, wqb, bq, Qh, 8192, 1024, 1024);
  gemm_bt_kernel<0><<<512, 256, 0, stream>>>(xb, wkb, bk, Kh, 8192, 1024, 1024);
  // Vt = Wv x^T -> [B,H,D,T]   (A = Wv rows = output d, B = x rows = t)
  gemm_bt_kernel<1><<<512, 256, 0, stream>>>(wvb, xb, bv, Vt, 1024, 8192, 1024);

  attn_kernel<<<dim3(16, 64), 256, 0, stream>>>(Qh, Kh, Vt, y);

  // out = y Wp^T + bp  (fp32)
  gemm_bt_kernel<2><<<512, 256, 0, stream>>>(y, wpb, bp, out, 8192, 1024, 1024);
}

// Round 2
// 315.096 us; speedup vs baseline: 1.3418x; 1.3418x over previous
//
#include <hip/hip_runtime.h>
#include <hip/hip_bf16.h>
#include <cstdint>
#include <cstddef>

#define TQ 2048
#define CDIM 1024
#define NH 16
#define HD 64

typedef __attribute__((ext_vector_type(8))) short bf16x8;
typedef __attribute__((ext_vector_type(4))) float f32x4;

__device__ __forceinline__ unsigned short f2bf(float f) {
  union { float f; unsigned u; } x; x.f = f;
  unsigned r = x.u + 0x7fffu + ((x.u >> 16) & 1u);
  return (unsigned short)(r >> 16);
}

__device__ __forceinline__ void gload_lds16(const void* g, void* l) {
  typedef __attribute__((address_space(1))) const void gv;
  typedef __attribute__((address_space(3))) void lv;
  __builtin_amdgcn_global_load_lds((gv*)g, (lv*)l, 16, 0, 0);
}

// ---------------- fp32 -> bf16 converts ----------------
__global__ void cvt_bf16_kernel(const float* __restrict__ in,
                                unsigned short* __restrict__ out, int n) {
  int stride = gridDim.x * blockDim.x;
  for (int i = blockIdx.x * blockDim.x + threadIdx.x; i * 4 < n; i += stride) {
    float4 v = *(const float4*)(in + (size_t)i * 4);
    ushort4 o;
    o.x = f2bf(v.x); o.y = f2bf(v.y); o.z = f2bf(v.z); o.w = f2bf(v.w);
    *(ushort4*)(out + (size_t)i * 4) = o;
  }
}

// 4 weight matrices (1M elems each) -> contiguous bf16 output
__global__ void cvt4_kernel(const float* __restrict__ w0, const float* __restrict__ w1,
                            const float* __restrict__ w2, const float* __restrict__ w3,
                            unsigned short* __restrict__ out) {
  int i = blockIdx.x * blockDim.x + threadIdx.x;  // vec4 index, 1M total
  int which = i >> 18;
  const float* src = which == 0 ? w0 : which == 1 ? w1 : which == 2 ? w2 : w3;
  int off = (i & 262143) * 4;
  float4 v = *(const float4*)(src + off);
  ushort4 o;
  o.x = f2bf(v.x); o.y = f2bf(v.y); o.z = f2bf(v.z); o.w = f2bf(v.w);
  *(ushort4*)(out + (size_t)i * 4) = o;
}

// ---------------- GEMM: C[M,N] = A[M,K] * Bt[N,K]^T (+bias), bf16 in ----------------
// EPI 2: f32 out -> [M,N] row-major, bias0[n]
// EPI 3: fused QKV: n<1024 -> Q [B,H,T,D] (bias0); n<2048 -> K [B,H,T,D] (bias1);
//        else -> V transposed [B,H,D,T] (bias2). outp = Qh base (Kh,Vt at fixed offsets).
template <int EPI>
__global__ __launch_bounds__(256) void gemm_bt_kernel(
    const unsigned short* __restrict__ A,
    const unsigned short* __restrict__ Bt,
    const float* __restrict__ b0, const float* __restrict__ b1,
    const float* __restrict__ b2,
    void* __restrict__ outp,
    int M, int N, int K) {
  __shared__ __align__(16) unsigned short As[128 * 64];
  __shared__ __align__(16) unsigned short Bs[128 * 64];

  const int nbm = M >> 7;
  const int nbn = N >> 7;
  const int nwg = nbm * nbn;
  int id = (int)blockIdx.x;
  const int cpx = nwg >> 3;  // nwg % 8 == 0 for all our grids
  id = (id & 7) * cpx + (id >> 3);
  const int tm = id % nbm;
  const int tn = id / nbm;

  const int tid = threadIdx.x;
  const int w = tid >> 6, lane = tid & 63;
  const int g = lane >> 4, c = lane & 15;
  const int wr = w >> 1, wc = w & 1;

  const unsigned short* Ab = A + (size_t)tm * 128 * K;
  const unsigned short* Bb = Bt + (size_t)tn * 128 * K;
  const int Kb = K * 2;

  f32x4 acc[4][4];
#pragma unroll
  for (int i = 0; i < 4; ++i)
#pragma unroll
    for (int j = 0; j < 4; ++j) acc[i][j] = (f32x4){0.f, 0.f, 0.f, 0.f};

  for (int kt = 0; kt < K; kt += 64) {
#pragma unroll
    for (int i = 0; i < 4; ++i) {
      const int seg = w * 4 + i;
      const int off = seg * 1024 + lane * 16;
      const int row = off >> 7;
      const int colB = off & 127;
      gload_lds16((const char*)Ab + (size_t)row * Kb + kt * 2 + colB,
                  (char*)As + seg * 1024);
      gload_lds16((const char*)Bb + (size_t)row * Kb + kt * 2 + colB,
                  (char*)Bs + seg * 1024);
    }
    __syncthreads();
#pragma unroll
    for (int ki = 0; ki < 2; ++ki) {
      bf16x8 af[4], bv[4];
#pragma unroll
      for (int mi = 0; mi < 4; ++mi)
        af[mi] = *(const bf16x8*)(As + (wr * 64 + mi * 16 + c) * 64 + ki * 32 + g * 8);
#pragma unroll
      for (int ni = 0; ni < 4; ++ni)
        bv[ni] = *(const bf16x8*)(Bs + (wc * 64 + ni * 16 + c) * 64 + ki * 32 + g * 8);
#pragma unroll
      for (int mi = 0; mi < 4; ++mi)
#pragma unroll
        for (int ni = 0; ni < 4; ++ni)
          acc[mi][ni] = __builtin_amdgcn_mfma_f32_16x16x32_bf16(
              af[mi], bv[ni], acc[mi][ni], 0, 0, 0);
    }
    __syncthreads();
  }

#pragma unroll
  for (int mi = 0; mi < 4; ++mi) {
#pragma unroll
    for (int ni = 0; ni < 4; ++ni) {
      const int n = tn * 128 + wc * 64 + ni * 16 + c;
#pragma unroll
      for (int e = 0; e < 4; ++e) {
        const int m = tm * 128 + wr * 64 + mi * 16 + g * 4 + e;
        float v = acc[mi][ni][e];
        if (EPI == 2) {
          v += b0[n];
          ((float*)outp)[(size_t)m * N + n] = v;
        } else {  // EPI == 3
          unsigned short* O = (unsigned short*)outp;
          if (n < 1024) {
            v += b0[n];
            size_t idx = ((size_t)(m >> 11) * NH + (n >> 6)) * (TQ * HD) +
                         (size_t)(m & (TQ - 1)) * HD + (n & (HD - 1));
            O[idx] = f2bf(v);
          } else if (n < 2048) {
            int nn = n - 1024;
            v += b1[nn];
            size_t idx = 8388608 + ((size_t)(m >> 11) * NH + (nn >> 6)) * (TQ * HD) +
                         (size_t)(m & (TQ - 1)) * HD + (nn & (HD - 1));
            O[idx] = f2bf(v);
          } else {
            int nn = n - 2048;
            v += b2[nn];
            size_t idx = 16777216 + ((size_t)(m >> 11) * 1024 + nn) * TQ + (m & (TQ - 1));
            O[idx] = f2bf(v);
          }
        }
      }
    }
  }
}

// ---------------- flash attention (causal), balanced + LDS-staged ----------------
// Q,K: [B,H,T,D] bf16 ; Vt: [B,H,D,T] bf16 ; Y: [B,T,C] bf16
// Block x = pair index p in 0..7 -> processes q-tiles p and 15-p (128 rows each).
// K/V tiles (64 kv) staged in LDS, double-buffered, XOR-swizzled via global source.
__global__ __launch_bounds__(256) void attn_kernel(
    const unsigned short* __restrict__ Q,
    const unsigned short* __restrict__ K,
    const unsigned short* __restrict__ Vt,
    unsigned short* __restrict__ Y) {
  __shared__ __align__(16) unsigned short Ks[2][4096];
  __shared__ __align__(16) unsigned short Vs[2][4096];
  __shared__ __align__(16) unsigned short Plds[4][32][72];

  const int tid = (int)threadIdx.x;
  const int w = tid >> 6, lane = tid & 63;
  const int g = lane >> 4, c = lane & 15;
  const int bh = (int)blockIdx.y;
  const int b = bh >> 4, h = bh & 15;

  const unsigned short* Qb = Q + (size_t)bh * TQ * HD;
  const char* Kb = (const char*)(K + (size_t)bh * TQ * HD);
  const char* Vb = (const char*)(Vt + (size_t)bh * HD * TQ);

  auto stage = [&](int buf, int kt) {
#pragma unroll
    for (int i = 0; i < 2; ++i) {
      const int o = (tid << 4) + (i << 12);       // byte offset in 8KB tile
      const int row = o >> 7;                     // 0..63
      const int scol = (o & 127) ^ ((row & 7) << 4);
      char* kdst = (char*)&Ks[buf][0] + ((w << 10) + (i << 12));  // wave-uniform
      char* vdst = (char*)&Vs[buf][0] + ((w << 10) + (i << 12));
      gload_lds16(Kb + (size_t)(kt * 64 + row) * 128 + scol, kdst);
      gload_lds16(Vb + (size_t)row * (TQ * 2) + kt * 128 + scol, vdst);
    }
  };

#pragma unroll 1
  for (int half = 0; half < 2; ++half) {
    const int qt = half ? (15 - (int)blockIdx.x) : (int)blockIdx.x;
    const int q0 = qt * 128 + w * 32;
    const int nkv = 2 * qt + 2;

    bf16x8 qf[2][2];
#pragma unroll
    for (int rb = 0; rb < 2; ++rb)
#pragma unroll
      for (int kd = 0; kd < 2; ++kd)
        qf[rb][kd] = *(const bf16x8*)(Qb + (size_t)(q0 + rb * 16 + c) * HD + kd * 32 + g * 8);

    f32x4 acc[2][4];
    float mr[2][4], lr[2][4];
#pragma unroll
    for (int i = 0; i < 2; ++i)
#pragma unroll
      for (int j = 0; j < 4; ++j) acc[i][j] = (f32x4){0.f, 0.f, 0.f, 0.f};
#pragma unroll
    for (int i = 0; i < 2; ++i)
#pragma unroll
      for (int e = 0; e < 4; ++e) { mr[i][e] = -3.0e38f; lr[i][e] = 0.f; }

    stage(0, 0);
    __syncthreads();

    for (int kt = 0; kt < nkv; ++kt) {
      const int cur = kt & 1;
      if (kt + 1 < nkv) stage(cur ^ 1, kt + 1);

      if (kt * 64 <= q0 + 31) {  // wave-uniform causal skip
        const char* Kt = (const char*)&Ks[cur][0];
        const char* Vtile = (const char*)&Vs[cur][0];

        // S = Q K^T : rows q0+rb*16+(g*4+e), cols kvb+cb*16+c
        f32x4 s[2][4];
#pragma unroll
        for (int i = 0; i < 2; ++i)
#pragma unroll
          for (int j = 0; j < 4; ++j) s[i][j] = (f32x4){0.f, 0.f, 0.f, 0.f};
#pragma unroll
        for (int cb = 0; cb < 4; ++cb)
#pragma unroll
          for (int kd = 0; kd < 2; ++kd) {
            bf16x8 kf = *(const bf16x8*)(Kt + (cb * 16 + c) * 128 +
                                         ((kd * 64 + g * 16) ^ ((c & 7) << 4)));
#pragma unroll
            for (int rb = 0; rb < 2; ++rb)
              s[rb][cb] = __builtin_amdgcn_mfma_f32_16x16x32_bf16(qf[rb][kd], kf, s[rb][cb], 0, 0, 0);
          }

        const bool maskT = (kt * 64 + 63 > q0);
#pragma unroll
        for (int rb = 0; rb < 2; ++rb)
#pragma unroll
          for (int cb = 0; cb < 4; ++cb)
#pragma unroll
            for (int e = 0; e < 4; ++e) {
              float v = s[rb][cb][e] * 0.125f;
              if (maskT) {
                int kv = kt * 64 + cb * 16 + c;
                int q = q0 + rb * 16 + g * 4 + e;
                if (kv > q) v = -3.0e38f;
              }
              s[rb][cb][e] = v;
            }

        float al[2][4];
#pragma unroll
        for (int rb = 0; rb < 2; ++rb)
#pragma unroll
          for (int e = 0; e < 4; ++e) {
            float v = fmaxf(fmaxf(s[rb][0][e], s[rb][1][e]), fmaxf(s[rb][2][e], s[rb][3][e]));
#pragma unroll
            for (int off = 1; off < 16; off <<= 1) v = fmaxf(v, __shfl_xor(v, off, 16));
            float mn = fmaxf(mr[rb][e], v);
            al[rb][e] = __expf(mr[rb][e] - mn);
            mr[rb][e] = mn;
          }

#pragma unroll
        for (int rb = 0; rb < 2; ++rb)
#pragma unroll
          for (int e = 0; e < 4; ++e) {
            float rs = 0.f;
#pragma unroll
            for (int cb = 0; cb < 4; ++cb) {
              float p = __expf(s[rb][cb][e] - mr[rb][e]);
              s[rb][cb][e] = p;
              rs += p;
            }
#pragma unroll
            for (int off = 1; off < 16; off <<= 1) rs += __shfl_xor(rs, off, 16);
            lr[rb][e] = lr[rb][e] * al[rb][e] + rs;
          }

#pragma unroll
        for (int rb = 0; rb < 2; ++rb)
#pragma unroll
          for (int db = 0; db < 4; ++db)
#pragma unroll
            for (int e = 0; e < 4; ++e) acc[rb][db][e] *= al[rb][e];

        // P -> LDS (bf16) -> A-fragments (same-wave DS ordering)
#pragma unroll
        for (int rb = 0; rb < 2; ++rb)
#pragma unroll
          for (int cb = 0; cb < 4; ++cb)
#pragma unroll
            for (int e = 0; e < 4; ++e)
              Plds[w][rb * 16 + g * 4 + e][cb * 16 + c] = f2bf(s[rb][cb][e]);

        bf16x8 pa[2][2];
#pragma unroll
        for (int rb = 0; rb < 2; ++rb)
#pragma unroll
          for (int ks = 0; ks < 2; ++ks)
            pa[rb][ks] = *(const bf16x8*)(&Plds[w][rb * 16 + c][ks * 32 + g * 8]);

#pragma unroll
        for (int db = 0; db < 4; ++db)
#pragma unroll
          for (int ks = 0; ks < 2; ++ks) {
            bf16x8 vf = *(const bf16x8*)(Vtile + (db * 16 + c) * 128 +
                                         ((ks * 64 + g * 16) ^ ((c & 7) << 4)));
#pragma unroll
            for (int rb = 0; rb < 2; ++rb)
              acc[rb][db] = __builtin_amdgcn_mfma_f32_16x16x32_bf16(pa[rb][ks], vf, acc[rb][db], 0, 0, 0);
          }
      }
      __syncthreads();
    }

    // epilogue: Y[b][t][h*64+d] = acc / l
#pragma unroll
    for (int rb = 0; rb < 2; ++rb)
#pragma unroll
      for (int db = 0; db < 4; ++db)
#pragma unroll
        for (int e = 0; e < 4; ++e) {
          float o = acc[rb][db][e] / lr[rb][e];
          int t = q0 + rb * 16 + g * 4 + e;
          int col = h * 64 + db * 16 + c;
          Y[(size_t)(b * TQ + t) * CDIM + col] = f2bf(o);
        }
  }
}

// ---------------- launcher ----------------
extern "C" void kernel_launch(void* const* d_in, const int* in_sizes, int n_in,
                              void* d_out, int out_size, void* d_ws, size_t ws_size,
                              hipStream_t stream) {
  (void)in_sizes; (void)n_in; (void)out_size; (void)ws_size;
  const float* x  = (const float*)d_in[0];
  const float* Wq = (const float*)d_in[1];
  const float* bq = (const float*)d_in[2];
  const float* Wk = (const float*)d_in[3];
  const float* bk = (const float*)d_in[4];
  const float* Wv = (const float*)d_in[5];
  const float* bv = (const float*)d_in[6];
  const float* Wp = (const float*)d_in[7];
  const float* bp = (const float*)d_in[8];
  float* out = (float*)d_out;

  char* ws = (char*)d_ws;
  unsigned short* xb  = (unsigned short*)(ws + 0);           // 16 MB
  unsigned short* wqb = (unsigned short*)(ws + 16777216);    // 4 x 2 MB contiguous
  unsigned short* wpb = (unsigned short*)(ws + 23068672);
  unsigned short* Qh  = (unsigned short*)(ws + 25165824);    // 16 MB [B,H,T,D]
  unsigned short* Vt  = (unsigned short*)(ws + 58720256);    // 16 MB [B,H,D,T]
  unsigned short* Kh  = (unsigned short*)(ws + 41943040);    // 16 MB [B,H,T,D]
  unsigned short* y   = (unsigned short*)(ws + 75497472);    // 16 MB [B,T,C]
  (void)Kh; (void)Vt;

  const int nx = 4 * TQ * CDIM;

  cvt_bf16_kernel<<<4096, 256, 0, stream>>>(x, xb, nx);
  cvt4_kernel<<<4096, 256, 0, stream>>>(Wq, Wk, Wv, Wp, wqb);

  // fused QKV: C = x [Wq;Wk;Wv]^T  (N = 3072), epilogue scatters Q,K,Vt
  gemm_bt_kernel<3><<<1536, 256, 0, stream>>>(xb, wqb, bq, bk, bv, Qh, 8192, 3072, 1024);

  attn_kernel<<<dim3(8, 64), 256, 0, stream>>>(Qh, Kh, Vt, y);

  // out = y Wp^T + bp  (fp32)
  gemm_bt_kernel<2><<<512, 256, 0, stream>>>(y, wpb, bp, bp, bp, out, 8192, 1024, 1024);
}

// Round 3
// 262.363 us; speedup vs baseline: 1.6114x; 1.2010x over previous
//
#include <hip/hip_runtime.h>
#include <hip/hip_bf16.h>
#include <cstdint>
#include <cstddef>

#define TQ 2048
#define CDIM 1024
#define NH 16
#define HD 64

typedef __attribute__((ext_vector_type(8))) short bf16x8;
typedef __attribute__((ext_vector_type(4))) float f32x4;

__device__ __forceinline__ unsigned short f2bf(float f) {
  union { float f; unsigned u; } x; x.f = f;
  unsigned r = x.u + 0x7fffu + ((x.u >> 16) & 1u);
  return (unsigned short)(r >> 16);
}

__device__ __forceinline__ void gload_lds16(const void* g, void* l) {
  typedef __attribute__((address_space(1))) const void gv;
  typedef __attribute__((address_space(3))) void lv;
  __builtin_amdgcn_global_load_lds((gv*)g, (lv*)l, 16, 0, 0);
}

// ---------------- fp32 -> bf16 converts ----------------
__global__ void cvt_bf16_kernel(const float* __restrict__ in,
                                unsigned short* __restrict__ out, int n) {
  int stride = gridDim.x * blockDim.x;
  for (int i = blockIdx.x * blockDim.x + threadIdx.x; i * 4 < n; i += stride) {
    float4 v = *(const float4*)(in + (size_t)i * 4);
    ushort4 o;
    o.x = f2bf(v.x); o.y = f2bf(v.y); o.z = f2bf(v.z); o.w = f2bf(v.w);
    *(ushort4*)(out + (size_t)i * 4) = o;
  }
}

// 4 weight matrices (1M elems each) -> contiguous bf16 output
__global__ void cvt4_kernel(const float* __restrict__ w0, const float* __restrict__ w1,
                            const float* __restrict__ w2, const float* __restrict__ w3,
                            unsigned short* __restrict__ out) {
  int i = blockIdx.x * blockDim.x + threadIdx.x;  // vec4 index, 1M total
  int which = i >> 18;
  const float* src = which == 0 ? w0 : which == 1 ? w1 : which == 2 ? w2 : w3;
  int off = (i & 262143) * 4;
  float4 v = *(const float4*)(src + off);
  ushort4 o;
  o.x = f2bf(v.x); o.y = f2bf(v.y); o.z = f2bf(v.z); o.w = f2bf(v.w);
  *(ushort4*)(out + (size_t)i * 4) = o;
}

// ---------------- GEMM: C[M,N] = A[M,K] * Bt[N,K]^T (+bias), bf16 in ----------------
// EPI 1: bf16 out -> [B,H,D,T]  (m=h*D+d, n=b*T+t), bias b0[m]  (coalesced V^T store)
// EPI 2: f32  out -> [M,N] row-major, bias b0[n]
// EPI 4: fused QK: n<1024 -> Q [B,H,T,D] (b0); else -> K at +8M elems (b1).
template <int EPI>
__global__ __launch_bounds__(256) void gemm_bt_kernel(
    const unsigned short* __restrict__ A,
    const unsigned short* __restrict__ Bt,
    const float* __restrict__ b0, const float* __restrict__ b1,
    void* __restrict__ outp,
    int M, int N, int K) {
  __shared__ __align__(16) unsigned short As[128 * 64];
  __shared__ __align__(16) unsigned short Bs[128 * 64];

  const int nbm = M >> 7;
  const int nbn = N >> 7;
  const int nwg = nbm * nbn;
  int id = (int)blockIdx.x;
  const int cpx = nwg >> 3;  // nwg % 8 == 0 for all our grids
  id = (id & 7) * cpx + (id >> 3);
  const int tm = id % nbm;
  const int tn = id / nbm;

  const int tid = threadIdx.x;
  const int w = tid >> 6, lane = tid & 63;
  const int g = lane >> 4, c = lane & 15;
  const int wr = w >> 1, wc = w & 1;

  const unsigned short* Ab = A + (size_t)tm * 128 * K;
  const unsigned short* Bb = Bt + (size_t)tn * 128 * K;
  const int Kb = K * 2;

  f32x4 acc[4][4];
#pragma unroll
  for (int i = 0; i < 4; ++i)
#pragma unroll
    for (int j = 0; j < 4; ++j) acc[i][j] = (f32x4){0.f, 0.f, 0.f, 0.f};

  for (int kt = 0; kt < K; kt += 64) {
#pragma unroll
    for (int i = 0; i < 4; ++i) {
      const int seg = w * 4 + i;
      const int off = seg * 1024 + lane * 16;
      const int row = off >> 7;
      const int colB = off & 127;
      gload_lds16((const char*)Ab + (size_t)row * Kb + kt * 2 + colB,
                  (char*)As + seg * 1024);
      gload_lds16((const char*)Bb + (size_t)row * Kb + kt * 2 + colB,
                  (char*)Bs + seg * 1024);
    }
    __syncthreads();
#pragma unroll
    for (int ki = 0; ki < 2; ++ki) {
      bf16x8 af[4], bv[4];
#pragma unroll
      for (int mi = 0; mi < 4; ++mi)
        af[mi] = *(const bf16x8*)(As + (wr * 64 + mi * 16 + c) * 64 + ki * 32 + g * 8);
#pragma unroll
      for (int ni = 0; ni < 4; ++ni)
        bv[ni] = *(const bf16x8*)(Bs + (wc * 64 + ni * 16 + c) * 64 + ki * 32 + g * 8);
#pragma unroll
      for (int mi = 0; mi < 4; ++mi)
#pragma unroll
        for (int ni = 0; ni < 4; ++ni)
          acc[mi][ni] = __builtin_amdgcn_mfma_f32_16x16x32_bf16(
              af[mi], bv[ni], acc[mi][ni], 0, 0, 0);
    }
    __syncthreads();
  }

#pragma unroll
  for (int mi = 0; mi < 4; ++mi) {
#pragma unroll
    for (int ni = 0; ni < 4; ++ni) {
      const int n = tn * 128 + wc * 64 + ni * 16 + c;
#pragma unroll
      for (int e = 0; e < 4; ++e) {
        const int m = tm * 128 + wr * 64 + mi * 16 + g * 4 + e;
        float v = acc[mi][ni][e];
        if (EPI == 1) {
          v += b0[m];
          size_t idx = ((size_t)(n >> 11) * (NH * HD) + m) * TQ + (n & (TQ - 1));
          ((unsigned short*)outp)[idx] = f2bf(v);
        } else if (EPI == 2) {
          v += b0[n];
          ((float*)outp)[(size_t)m * N + n] = v;
        } else {  // EPI == 4: fused QK
          unsigned short* O = (unsigned short*)outp;
          if (n < 1024) {
            v += b0[n];
            size_t idx = ((size_t)(m >> 11) * NH + (n >> 6)) * (TQ * HD) +
                         (size_t)(m & (TQ - 1)) * HD + (n & (HD - 1));
            O[idx] = f2bf(v);
          } else {
            int nn = n - 1024;
            v += b1[nn];
            size_t idx = 8388608 + ((size_t)(m >> 11) * NH + (nn >> 6)) * (TQ * HD) +
                         (size_t)(m & (TQ - 1)) * HD + (nn & (HD - 1));
            O[idx] = f2bf(v);
          }
        }
      }
    }
  }
}

// ---------------- flash attention (causal), balanced + LDS-staged ----------------
// Q,K: [B,H,T,D] bf16 ; Vt: [B,H,D,T] bf16 ; Y: [B,T,C] bf16
// Block x = pair index p in 0..7 -> processes q-tiles p and 15-p (128 rows each).
__global__ __launch_bounds__(256) void attn_kernel(
    const unsigned short* __restrict__ Q,
    const unsigned short* __restrict__ K,
    const unsigned short* __restrict__ Vt,
    unsigned short* __restrict__ Y) {
  __shared__ __align__(16) unsigned short Ks[2][4096];
  __shared__ __align__(16) unsigned short Vs[2][4096];
  __shared__ __align__(16) unsigned short Plds[4][32][72];

  const int tid = (int)threadIdx.x;
  const int w = tid >> 6, lane = tid & 63;
  const int g = lane >> 4, c = lane & 15;
  const int bh = (int)blockIdx.y;
  const int b = bh >> 4, h = bh & 15;

  const unsigned short* Qb = Q + (size_t)bh * TQ * HD;
  const char* Kb = (const char*)(K + (size_t)bh * TQ * HD);
  const char* Vb = (const char*)(Vt + (size_t)bh * HD * TQ);

  auto stage = [&](int buf, int kt) {
#pragma unroll
    for (int i = 0; i < 2; ++i) {
      const int o = (tid << 4) + (i << 12);       // byte offset in 8KB tile
      const int row = o >> 7;                     // 0..63
      const int scol = (o & 127) ^ ((row & 7) << 4);
      char* kdst = (char*)&Ks[buf][0] + ((w << 10) + (i << 12));  // wave-uniform
      char* vdst = (char*)&Vs[buf][0] + ((w << 10) + (i << 12));
      gload_lds16(Kb + (size_t)(kt * 64 + row) * 128 + scol, kdst);
      gload_lds16(Vb + (size_t)row * (TQ * 2) + kt * 128 + scol, vdst);
    }
  };

#pragma unroll 1
  for (int half = 0; half < 2; ++half) {
    const int qt = half ? (15 - (int)blockIdx.x) : (int)blockIdx.x;
    const int q0 = qt * 128 + w * 32;
    const int nkv = 2 * qt + 2;

    bf16x8 qf[2][2];
#pragma unroll
    for (int rb = 0; rb < 2; ++rb)
#pragma unroll
      for (int kd = 0; kd < 2; ++kd)
        qf[rb][kd] = *(const bf16x8*)(Qb + (size_t)(q0 + rb * 16 + c) * HD + kd * 32 + g * 8);

    f32x4 acc[2][4];
    float mr[2][4], lr[2][4];
#pragma unroll
    for (int i = 0; i < 2; ++i)
#pragma unroll
      for (int j = 0; j < 4; ++j) acc[i][j] = (f32x4){0.f, 0.f, 0.f, 0.f};
#pragma unroll
    for (int i = 0; i < 2; ++i)
#pragma unroll
      for (int e = 0; e < 4; ++e) { mr[i][e] = -3.0e38f; lr[i][e] = 0.f; }

    stage(0, 0);
    __syncthreads();

    for (int kt = 0; kt < nkv; ++kt) {
      const int cur = kt & 1;
      if (kt + 1 < nkv) stage(cur ^ 1, kt + 1);

      if (kt * 64 <= q0 + 31) {  // wave-uniform causal skip
        const char* Kt = (const char*)&Ks[cur][0];
        const char* Vtile = (const char*)&Vs[cur][0];

        f32x4 s[2][4];
#pragma unroll
        for (int i = 0; i < 2; ++i)
#pragma unroll
          for (int j = 0; j < 4; ++j) s[i][j] = (f32x4){0.f, 0.f, 0.f, 0.f};
#pragma unroll
        for (int cb = 0; cb < 4; ++cb)
#pragma unroll
          for (int kd = 0; kd < 2; ++kd) {
            bf16x8 kf = *(const bf16x8*)(Kt + (cb * 16 + c) * 128 +
                                         ((kd * 64 + g * 16) ^ ((c & 7) << 4)));
#pragma unroll
            for (int rb = 0; rb < 2; ++rb)
              s[rb][cb] = __builtin_amdgcn_mfma_f32_16x16x32_bf16(qf[rb][kd], kf, s[rb][cb], 0, 0, 0);
          }

        const bool maskT = (kt * 64 + 63 > q0);
#pragma unroll
        for (int rb = 0; rb < 2; ++rb)
#pragma unroll
          for (int cb = 0; cb < 4; ++cb)
#pragma unroll
            for (int e = 0; e < 4; ++e) {
              float v = s[rb][cb][e] * 0.125f;
              if (maskT) {
                int kv = kt * 64 + cb * 16 + c;
                int q = q0 + rb * 16 + g * 4 + e;
                if (kv > q) v = -3.0e38f;
              }
              s[rb][cb][e] = v;
            }

        float al[2][4];
#pragma unroll
        for (int rb = 0; rb < 2; ++rb)
#pragma unroll
          for (int e = 0; e < 4; ++e) {
            float v = fmaxf(fmaxf(s[rb][0][e], s[rb][1][e]), fmaxf(s[rb][2][e], s[rb][3][e]));
#pragma unroll
            for (int off = 1; off < 16; off <<= 1) v = fmaxf(v, __shfl_xor(v, off, 16));
            float mn = fmaxf(mr[rb][e], v);
            al[rb][e] = __expf(mr[rb][e] - mn);
            mr[rb][e] = mn;
          }

#pragma unroll
        for (int rb = 0; rb < 2; ++rb)
#pragma unroll
          for (int e = 0; e < 4; ++e) {
            float rs = 0.f;
#pragma unroll
            for (int cb = 0; cb < 4; ++cb) {
              float p = __expf(s[rb][cb][e] - mr[rb][e]);
              s[rb][cb][e] = p;
              rs += p;
            }
#pragma unroll
            for (int off = 1; off < 16; off <<= 1) rs += __shfl_xor(rs, off, 16);
            lr[rb][e] = lr[rb][e] * al[rb][e] + rs;
          }

#pragma unroll
        for (int rb = 0; rb < 2; ++rb)
#pragma unroll
          for (int db = 0; db < 4; ++db)
#pragma unroll
            for (int e = 0; e < 4; ++e) acc[rb][db][e] *= al[rb][e];

        // P -> LDS (bf16) -> A-fragments (same-wave DS ordering)
#pragma unroll
        for (int rb = 0; rb < 2; ++rb)
#pragma unroll
          for (int cb = 0; cb < 4; ++cb)
#pragma unroll
            for (int e = 0; e < 4; ++e)
              Plds[w][rb * 16 + g * 4 + e][cb * 16 + c] = f2bf(s[rb][cb][e]);

        bf16x8 pa[2][2];
#pragma unroll
        for (int rb = 0; rb < 2; ++rb)
#pragma unroll
          for (int ks = 0; ks < 2; ++ks)
            pa[rb][ks] = *(const bf16x8*)(&Plds[w][rb * 16 + c][ks * 32 + g * 8]);

#pragma unroll
        for (int db = 0; db < 4; ++db)
#pragma unroll
          for (int ks = 0; ks < 2; ++ks) {
            bf16x8 vf = *(const bf16x8*)(Vtile + (db * 16 + c) * 128 +
                                         ((ks * 64 + g * 16) ^ ((c & 7) << 4)));
#pragma unroll
            for (int rb = 0; rb < 2; ++rb)
              acc[rb][db] = __builtin_amdgcn_mfma_f32_16x16x32_bf16(pa[rb][ks], vf, acc[rb][db], 0, 0, 0);
          }
      }
      __syncthreads();
    }

    // epilogue: Y[b][t][h*64+d] = acc / l
#pragma unroll
    for (int rb = 0; rb < 2; ++rb)
#pragma unroll
      for (int db = 0; db < 4; ++db)
#pragma unroll
        for (int e = 0; e < 4; ++e) {
          float o = acc[rb][db][e] / lr[rb][e];
          int t = q0 + rb * 16 + g * 4 + e;
          int col = h * 64 + db * 16 + c;
          Y[(size_t)(b * TQ + t) * CDIM + col] = f2bf(o);
        }
  }
}

// ---------------- launcher ----------------
extern "C" void kernel_launch(void* const* d_in, const int* in_sizes, int n_in,
                              void* d_out, int out_size, void* d_ws, size_t ws_size,
                              hipStream_t stream) {
  (void)in_sizes; (void)n_in; (void)out_size; (void)ws_size;
  const float* x  = (const float*)d_in[0];
  const float* Wq = (const float*)d_in[1];
  const float* bq = (const float*)d_in[2];
  const float* Wk = (const float*)d_in[3];
  const float* bk = (const float*)d_in[4];
  const float* Wv = (const float*)d_in[5];
  const float* bv = (const float*)d_in[6];
  const float* Wp = (const float*)d_in[7];
  const float* bp = (const float*)d_in[8];
  float* out = (float*)d_out;

  char* ws = (char*)d_ws;
  unsigned short* xb  = (unsigned short*)(ws + 0);           // 16 MB
  unsigned short* wqb = (unsigned short*)(ws + 16777216);    // Wq,Wk,Wv,Wp contiguous (2 MB each)
  unsigned short* wvb = (unsigned short*)(ws + 20971520);
  unsigned short* wpb = (unsigned short*)(ws + 23068672);
  unsigned short* Qh  = (unsigned short*)(ws + 25165824);    // 16 MB [B,H,T,D]; Kh at +16MB
  unsigned short* Kh  = (unsigned short*)(ws + 41943040);
  unsigned short* Vt  = (unsigned short*)(ws + 58720256);    // 16 MB [B,H,D,T]
  unsigned short* y   = (unsigned short*)(ws + 75497472);    // 16 MB [B,T,C]

  const int nx = 4 * TQ * CDIM;

  cvt_bf16_kernel<<<4096, 256, 0, stream>>>(x, xb, nx);
  cvt4_kernel<<<4096, 256, 0, stream>>>(Wq, Wk, Wv, Wp, wqb);

  // fused Q+K: C = x [Wq;Wk]^T (N=2048); epilogue scatters Q->Qh, K->Qh+8M (coalesced)
  gemm_bt_kernel<4><<<1024, 256, 0, stream>>>(xb, wqb, bq, bk, Qh, 8192, 2048, 1024);
  // V^T: [B,H,D,T] = Wv x^T (M=1024, N=8192); stores coalesced along T
  gemm_bt_kernel<1><<<512, 256, 0, stream>>>(wvb, xb, bv, bv, Vt, 1024, 8192, 1024);

  attn_kernel<<<dim3(8, 64), 256, 0, stream>>>(Qh, Kh, Vt, y);

  // out = y Wp^T + bp  (fp32)
  gemm_bt_kernel<2><<<512, 256, 0, stream>>>(y, wpb, bp, bp, out, 8192, 1024, 1024);
}

// Round 4
// 205.615 us; speedup vs baseline: 2.0562x; 1.2760x over previous
//
#include <hip/hip_runtime.h>
#include <hip/hip_bf16.h>
#include <cstdint>
#include <cstddef>

#define TQ 2048
#define CDIM 1024
#define NH 16
#define HD 64

typedef __attribute__((ext_vector_type(8))) short bf16x8;
typedef __attribute__((ext_vector_type(4))) float f32x4;
typedef __attribute__((ext_vector_type(16))) float f32x16;

__device__ __forceinline__ unsigned short f2bf(float f) {
  union { float f; unsigned u; } x; x.f = f;
  unsigned r = x.u + 0x7fffu + ((x.u >> 16) & 1u);
  return (unsigned short)(r >> 16);
}

__device__ __forceinline__ unsigned cvtpk(float lo, float hi) {
  unsigned r;
  asm("v_cvt_pk_bf16_f32 %0, %1, %2" : "=v"(r) : "v"(lo), "v"(hi));
  return r;
}

__device__ __forceinline__ void plswap(unsigned& x, unsigned& y) {
  asm("v_permlane32_swap_b32 %0, %1" : "+v"(x), "+v"(y));
}

__device__ __forceinline__ float exp2_fast(float x) {
  float r;
  asm("v_exp_f32 %0, %1" : "=v"(r) : "v"(x));
  return r;
}

__device__ __forceinline__ void gload_lds16(const void* g, void* l) {
  typedef __attribute__((address_space(1))) const void gv;
  typedef __attribute__((address_space(3))) void lv;
  __builtin_amdgcn_global_load_lds((gv*)g, (lv*)l, 16, 0, 0);
}

// ---------------- fp32 -> bf16 converts ----------------
__global__ void cvt_bf16_kernel(const float* __restrict__ in,
                                unsigned short* __restrict__ out, int n) {
  int stride = gridDim.x * blockDim.x;
  for (int i = blockIdx.x * blockDim.x + threadIdx.x; i * 4 < n; i += stride) {
    float4 v = *(const float4*)(in + (size_t)i * 4);
    ushort4 o;
    o.x = f2bf(v.x); o.y = f2bf(v.y); o.z = f2bf(v.z); o.w = f2bf(v.w);
    *(ushort4*)(out + (size_t)i * 4) = o;
  }
}

__global__ void cvt4_kernel(const float* __restrict__ w0, const float* __restrict__ w1,
                            const float* __restrict__ w2, const float* __restrict__ w3,
                            unsigned short* __restrict__ out) {
  int i = blockIdx.x * blockDim.x + threadIdx.x;  // vec4 index, 1M total
  int which = i >> 18;
  const float* src = which == 0 ? w0 : which == 1 ? w1 : which == 2 ? w2 : w3;
  int off = (i & 262143) * 4;
  float4 v = *(const float4*)(src + off);
  ushort4 o;
  o.x = f2bf(v.x); o.y = f2bf(v.y); o.z = f2bf(v.z); o.w = f2bf(v.w);
  *(ushort4*)(out + (size_t)i * 4) = o;
}

// ---------------- GEMM: C[M,N] = A[M,K] * Bt[N,K]^T (+bias), bf16 in ----------------
// EPI 1: bf16 out -> [B,H,D,T]  (m=h*D+d, n=b*T+t), bias b0[m]  (coalesced V^T store)
// EPI 2: f32  out -> [M,N] row-major, bias b0[n]
// EPI 4: fused QK: n<1024 -> Q [B,H,T,D] (b0); else -> K at +8M elems (b1).
template <int EPI>
__global__ __launch_bounds__(256) void gemm_bt_kernel(
    const unsigned short* __restrict__ A,
    const unsigned short* __restrict__ Bt,
    const float* __restrict__ b0, const float* __restrict__ b1,
    void* __restrict__ outp,
    int M, int N, int K) {
  __shared__ __align__(16) unsigned short As[128 * 64];
  __shared__ __align__(16) unsigned short Bs[128 * 64];

  const int nbm = M >> 7;
  const int nbn = N >> 7;
  const int nwg = nbm * nbn;
  int id = (int)blockIdx.x;
  const int cpx = nwg >> 3;  // nwg % 8 == 0 for all our grids
  id = (id & 7) * cpx + (id >> 3);
  const int tm = id % nbm;
  const int tn = id / nbm;

  const int tid = threadIdx.x;
  const int w = tid >> 6, lane = tid & 63;
  const int g = lane >> 4, c = lane & 15;
  const int wr = w >> 1, wc = w & 1;

  const unsigned short* Ab = A + (size_t)tm * 128 * K;
  const unsigned short* Bb = Bt + (size_t)tn * 128 * K;
  const int Kb = K * 2;

  f32x4 acc[4][4];
#pragma unroll
  for (int i = 0; i < 4; ++i)
#pragma unroll
    for (int j = 0; j < 4; ++j) acc[i][j] = (f32x4){0.f, 0.f, 0.f, 0.f};

  for (int kt = 0; kt < K; kt += 64) {
#pragma unroll
    for (int i = 0; i < 4; ++i) {
      const int seg = w * 4 + i;
      const int off = seg * 1024 + lane * 16;
      const int row = off >> 7;
      const int colB = off & 127;
      gload_lds16((const char*)Ab + (size_t)row * Kb + kt * 2 + colB,
                  (char*)As + seg * 1024);
      gload_lds16((const char*)Bb + (size_t)row * Kb + kt * 2 + colB,
                  (char*)Bs + seg * 1024);
    }
    __syncthreads();
#pragma unroll
    for (int ki = 0; ki < 2; ++ki) {
      bf16x8 af[4], bv[4];
#pragma unroll
      for (int mi = 0; mi < 4; ++mi)
        af[mi] = *(const bf16x8*)(As + (wr * 64 + mi * 16 + c) * 64 + ki * 32 + g * 8);
#pragma unroll
      for (int ni = 0; ni < 4; ++ni)
        bv[ni] = *(const bf16x8*)(Bs + (wc * 64 + ni * 16 + c) * 64 + ki * 32 + g * 8);
#pragma unroll
      for (int mi = 0; mi < 4; ++mi)
#pragma unroll
        for (int ni = 0; ni < 4; ++ni)
          acc[mi][ni] = __builtin_amdgcn_mfma_f32_16x16x32_bf16(
              af[mi], bv[ni], acc[mi][ni], 0, 0, 0);
    }
    __syncthreads();
  }

#pragma unroll
  for (int mi = 0; mi < 4; ++mi) {
#pragma unroll
    for (int ni = 0; ni < 4; ++ni) {
      const int n = tn * 128 + wc * 64 + ni * 16 + c;
#pragma unroll
      for (int e = 0; e < 4; ++e) {
        const int m = tm * 128 + wr * 64 + mi * 16 + g * 4 + e;
        float v = acc[mi][ni][e];
        if (EPI == 1) {
          v += b0[m];
          size_t idx = ((size_t)(n >> 11) * (NH * HD) + m) * TQ + (n & (TQ - 1));
          ((unsigned short*)outp)[idx] = f2bf(v);
        } else if (EPI == 2) {
          v += b0[n];
          ((float*)outp)[(size_t)m * N + n] = v;
        } else {  // EPI == 4: fused QK
          unsigned short* O = (unsigned short*)outp;
          if (n < 1024) {
            v += b0[n];
            size_t idx = ((size_t)(m >> 11) * NH + (n >> 6)) * (TQ * HD) +
                         (size_t)(m & (TQ - 1)) * HD + (n & (HD - 1));
            O[idx] = f2bf(v);
          } else {
            int nn = n - 1024;
            v += b1[nn];
            size_t idx = 8388608 + ((size_t)(m >> 11) * NH + (nn >> 6)) * (TQ * HD) +
                         (size_t)(m & (TQ - 1)) * HD + (nn & (HD - 1));
            O[idx] = f2bf(v);
          }
        }
      }
    }
  }
}

// ---------------- flash attention (causal), swapped-QK^T in-register softmax ----------
// Q,K: [B,H,T,D] bf16 ; Vt: [B,H,D,T] bf16 ; Y: [B,T,C] bf16
// Block x = pair p: q-tiles p and 15-p. Wave w owns 32 q-rows; q = lane&31 per lane.
// S^T = mfma32x32(K,Q): lane holds 32 P-values of its q-row (hi=lane>>5 splits kv).
// O^T = mfma32x32(V^T, P): col = q = lane&31 -> m,l,rescale all lane-local.
__global__ __launch_bounds__(256) void attn_kernel(
    const unsigned short* __restrict__ Q,
    const unsigned short* __restrict__ K,
    const unsigned short* __restrict__ Vt,
    unsigned short* __restrict__ Y) {
  __shared__ __align__(16) unsigned short Ks[2][4096];
  __shared__ __align__(16) unsigned short Vs[2][4096];

  const int tid = (int)threadIdx.x;
  const int w = tid >> 6, lane = tid & 63;
  const int l31 = lane & 31, hi = lane >> 5;
  const int sx = (l31 & 7) << 4;  // LDS XOR swizzle term (row&7)<<4
  const int bh = (int)blockIdx.y;
  const int b = bh >> 4, h = bh & 15;

  const unsigned short* Qb = Q + (size_t)bh * TQ * HD;
  const char* Kb = (const char*)(K + (size_t)bh * TQ * HD);
  const char* Vb = (const char*)(Vt + (size_t)bh * HD * TQ);

  auto stage = [&](int buf, int kt) {
#pragma unroll
    for (int i = 0; i < 2; ++i) {
      const int o = (tid << 4) + (i << 12);       // byte offset in 8KB tile
      const int row = o >> 7;                     // 0..63
      const int scol = (o & 127) ^ ((row & 7) << 4);
      char* kdst = (char*)&Ks[buf][0] + ((w << 10) + (i << 12));  // wave-uniform
      char* vdst = (char*)&Vs[buf][0] + ((w << 10) + (i << 12));
      gload_lds16(Kb + (size_t)(kt * 64 + row) * 128 + scol, kdst);
      gload_lds16(Vb + (size_t)row * (TQ * 2) + kt * 128 + scol, vdst);
    }
  };

  const float SC = 0.18033688f;  // 0.125 * log2(e): softmax in log2 domain

#pragma unroll 1
  for (int half = 0; half < 2; ++half) {
    const int qt = half ? (15 - (int)blockIdx.x) : (int)blockIdx.x;
    const int q0 = qt * 128 + w * 32;
    const int qg = q0 + l31;      // this lane's q-row
    const int nkv = 2 * qt + 2;

    // Q as B-operand: col q = l31, k-slice d = dk*16 + hi*8 + e
    bf16x8 qf[4];
#pragma unroll
    for (int dk = 0; dk < 4; ++dk)
      qf[dk] = *(const bf16x8*)(Qb + (size_t)qg * HD + dk * 16 + hi * 8);

    f32x16 oac[2];
#pragma unroll
    for (int nb = 0; nb < 2; ++nb)
#pragma unroll
      for (int r = 0; r < 16; ++r) oac[nb][r] = 0.f;
    float mr = -3.0e38f, lr = 0.f;

    stage(0, 0);
    __syncthreads();

    for (int kt = 0; kt < nkv; ++kt) {
      const int cur = kt & 1;
      if (kt + 1 < nkv) stage(cur ^ 1, kt + 1);

      if (kt * 64 <= q0 + 31) {  // wave-uniform causal skip
        const char* Kt = (const char*)&Ks[cur][0];
        const char* Vtile = (const char*)&Vs[cur][0];

        // S^T tiles: s0 = kv[0,32), s1 = kv[32,64); lane holds col q=l31,
        // rows kv = (r&3)+8*(r>>2)+4*hi (+32 for s1)
        f32x16 s0, s1;
#pragma unroll
        for (int r = 0; r < 16; ++r) { s0[r] = 0.f; s1[r] = 0.f; }
#pragma unroll
        for (int dk = 0; dk < 4; ++dk) {
          bf16x8 kf0 = *(const bf16x8*)(Kt + l31 * 128 + ((dk * 32 + hi * 16) ^ sx));
          bf16x8 kf1 = *(const bf16x8*)(Kt + (32 + l31) * 128 + ((dk * 32 + hi * 16) ^ sx));
          s0 = __builtin_amdgcn_mfma_f32_32x32x16_bf16(kf0, qf[dk], s0, 0, 0, 0);
          s1 = __builtin_amdgcn_mfma_f32_32x32x16_bf16(kf1, qf[dk], s1, 0, 0, 0);
        }

        const bool maskT = (kt * 64 + 63 > q0);
        if (maskT) {
#pragma unroll
          for (int r = 0; r < 16; ++r) {
            int kv0 = kt * 64 + ((r & 3) + 8 * (r >> 2)) + 4 * hi;
            s0[r] = (kv0 <= qg) ? s0[r] * SC : -3.0e38f;
            s1[r] = (kv0 + 32 <= qg) ? s1[r] * SC : -3.0e38f;
          }
        } else {
#pragma unroll
          for (int r = 0; r < 16; ++r) { s0[r] *= SC; s1[r] *= SC; }
        }

        // row max: in-lane 32 + partner exchange
        float mt_ = s0[0];
#pragma unroll
        for (int r = 1; r < 16; ++r) mt_ = fmaxf(mt_, s0[r]);
#pragma unroll
        for (int r = 0; r < 16; ++r) mt_ = fmaxf(mt_, s1[r]);
        mt_ = fmaxf(mt_, __shfl_xor(mt_, 32));
        const float mn = fmaxf(mr, mt_);
        const float al = exp2_fast(mr - mn);
        mr = mn;

        // P = exp2(s - mn), row sum
        float rs = 0.f;
#pragma unroll
        for (int r = 0; r < 16; ++r) { s0[r] = exp2_fast(s0[r] - mn); rs += s0[r]; }
#pragma unroll
        for (int r = 0; r < 16; ++r) { s1[r] = exp2_fast(s1[r] - mn); rs += s1[r]; }
        rs += __shfl_xor(rs, 32);
        lr = lr * al + rs;

        // rescale O (lane-local: col q = l31)
#pragma unroll
        for (int nb = 0; nb < 2; ++nb)
#pragma unroll
          for (int r = 0; r < 16; ++r) oac[nb][r] *= al;

        // pack P -> bf16 B-fragments (k-slice kv = ks*16 + hi*8 + e)
        bf16x8 pf[4];
        {
          unsigned a0 = cvtpk(s0[0], s0[1]), b0 = cvtpk(s0[2], s0[3]);
          unsigned c0 = cvtpk(s0[4], s0[5]), d0 = cvtpk(s0[6], s0[7]);
          plswap(a0, c0); plswap(b0, d0);
          unsigned a1 = cvtpk(s0[8], s0[9]), b1 = cvtpk(s0[10], s0[11]);
          unsigned c1 = cvtpk(s0[12], s0[13]), d1 = cvtpk(s0[14], s0[15]);
          plswap(a1, c1); plswap(b1, d1);
          unsigned a2 = cvtpk(s1[0], s1[1]), b2 = cvtpk(s1[2], s1[3]);
          unsigned c2 = cvtpk(s1[4], s1[5]), d2 = cvtpk(s1[6], s1[7]);
          plswap(a2, c2); plswap(b2, d2);
          unsigned a3 = cvtpk(s1[8], s1[9]), b3 = cvtpk(s1[10], s1[11]);
          unsigned c3 = cvtpk(s1[12], s1[13]), d3 = cvtpk(s1[14], s1[15]);
          plswap(a3, c3); plswap(b3, d3);
          union { unsigned u[4]; bf16x8 v; } t;
          t.u[0] = a0; t.u[1] = b0; t.u[2] = c0; t.u[3] = d0; pf[0] = t.v;
          t.u[0] = a1; t.u[1] = b1; t.u[2] = c1; t.u[3] = d1; pf[1] = t.v;
          t.u[0] = a2; t.u[1] = b2; t.u[2] = c2; t.u[3] = d2; pf[2] = t.v;
          t.u[0] = a3; t.u[1] = b3; t.u[2] = c3; t.u[3] = d3; pf[3] = t.v;
        }

        // O^T += V^T · P : A = Vt rows (d), B = P cols (q)
#pragma unroll
        for (int nb = 0; nb < 2; ++nb)
#pragma unroll
          for (int ks = 0; ks < 4; ++ks) {
            bf16x8 vf = *(const bf16x8*)(Vtile + (nb * 32 + l31) * 128 +
                                         ((ks * 32 + hi * 16) ^ sx));
            oac[nb] = __builtin_amdgcn_mfma_f32_32x32x16_bf16(vf, pf[ks], oac[nb], 0, 0, 0);
          }
      }
      __syncthreads();
    }

    // epilogue: Y[b][t = qg][h*64 + d], d = (r&3)+8*(r>>2)+4*hi + 32*nb; /l; pack pairs
    float inv;
    asm("v_rcp_f32 %0, %1" : "=v"(inv) : "v"(lr));
    unsigned short* Yrow = Y + (size_t)(b * TQ + qg) * CDIM + h * 64;
#pragma unroll
    for (int nb = 0; nb < 2; ++nb)
#pragma unroll
      for (int j = 0; j < 8; ++j) {
        const int dbase = ((2 * j) & 3) + 8 * (j >> 1);
        unsigned lo = f2bf(oac[nb][2 * j] * inv);
        unsigned hi2 = f2bf(oac[nb][2 * j + 1] * inv);
        *(unsigned*)(Yrow + nb * 32 + dbase + 4 * hi) = lo | (hi2 << 16);
      }
  }
}

// ---------------- launcher ----------------
extern "C" void kernel_launch(void* const* d_in, const int* in_sizes, int n_in,
                              void* d_out, int out_size, void* d_ws, size_t ws_size,
                              hipStream_t stream) {
  (void)in_sizes; (void)n_in; (void)out_size; (void)ws_size;
  const float* x  = (const float*)d_in[0];
  const float* Wq = (const float*)d_in[1];
  const float* bq = (const float*)d_in[2];
  const float* Wk = (const float*)d_in[3];
  const float* bk = (const float*)d_in[4];
  const float* Wv = (const float*)d_in[5];
  const float* bv = (const float*)d_in[6];
  const float* Wp = (const float*)d_in[7];
  const float* bp = (const float*)d_in[8];
  float* out = (float*)d_out;

  char* ws = (char*)d_ws;
  unsigned short* xb  = (unsigned short*)(ws + 0);           // 16 MB
  unsigned short* wqb = (unsigned short*)(ws + 16777216);    // Wq,Wk,Wv,Wp contiguous (2 MB each)
  unsigned short* wvb = (unsigned short*)(ws + 20971520);
  unsigned short* wpb = (unsigned short*)(ws + 23068672);
  unsigned short* Qh  = (unsigned short*)(ws + 25165824);    // 16 MB [B,H,T,D]; Kh at +16MB
  unsigned short* Kh  = (unsigned short*)(ws + 41943040);
  unsigned short* Vt  = (unsigned short*)(ws + 58720256);    // 16 MB [B,H,D,T]
  unsigned short* y   = (unsigned short*)(ws + 75497472);    // 16 MB [B,T,C]

  const int nx = 4 * TQ * CDIM;

  cvt_bf16_kernel<<<4096, 256, 0, stream>>>(x, xb, nx);
  cvt4_kernel<<<4096, 256, 0, stream>>>(Wq, Wk, Wv, Wp, wqb);

  // fused Q+K: C = x [Wq;Wk]^T (N=2048); epilogue scatters Q->Qh, K->Qh+8M (coalesced)
  gemm_bt_kernel<4><<<1024, 256, 0, stream>>>(xb, wqb, bq, bk, Qh, 8192, 2048, 1024);
  // V^T: [B,H,D,T] = Wv x^T (M=1024, N=8192); stores coalesced along T
  gemm_bt_kernel<1><<<512, 256, 0, stream>>>(wvb, xb, bv, bv, Vt, 1024, 8192, 1024);

  attn_kernel<<<dim3(8, 64), 256, 0, stream>>>(Qh, Kh, Vt, y);

  // out = y Wp^T + bp  (fp32)
  gemm_bt_kernel<2><<<512, 256, 0, stream>>>(y, wpb, bp, bp, out, 8192, 1024, 1024);
}